// Round 2
// baseline (5643.904 us; speedup 1.0000x reference)
//
#include <hip/hip_runtime.h>

#define F_IN  128
#define F_HID 8
#define F_OUT 16

// NOTE: harness uploads int64 inputs as int32 — edge_index is const int* [2][E].

// ---------------- degree ----------------
__global__ void init_deg(float* __restrict__ deg, int n) {
    int i = blockIdx.x * blockDim.x + threadIdx.x;
    if (i < n) deg[i] = 1.0f;  // self-loop
}

__global__ void deg_count(const int* __restrict__ ei, float* __restrict__ deg, int E) {
    int e = blockIdx.x * blockDim.x + threadIdx.x;
    if (e < E) atomicAdd(&deg[ei[E + e]], 1.0f);
}

__global__ void rsqrt_k(float* __restrict__ deg, int n) {
    int i = blockIdx.x * blockDim.x + threadIdx.x;
    if (i < n) deg[i] = rsqrtf(deg[i]);  // deg >= 1 always (self-loops)
}

// ---------------- layer-1 GEMM: h1 = x @ W1 ; agg1 = h1 * dis^2 (self-loop) ----------------
__global__ __launch_bounds__(256) void gemm1(const float* __restrict__ x,
                                             const float* __restrict__ W1,
                                             const float* __restrict__ dis,
                                             float* __restrict__ h1,
                                             float* __restrict__ agg1, int n) {
    __shared__ float w[F_IN * F_HID];  // 4 KB
    for (int i = threadIdx.x; i < F_IN * F_HID; i += blockDim.x) w[i] = W1[i];
    __syncthreads();
    int node = blockIdx.x * blockDim.x + threadIdx.x;
    if (node >= n) return;
    const float4* xr = (const float4*)(x + (size_t)node * F_IN);
    float acc[F_HID];
#pragma unroll
    for (int f = 0; f < F_HID; f++) acc[f] = 0.0f;
#pragma unroll
    for (int j = 0; j < F_IN / 4; j++) {
        float4 v = xr[j];
        const float* wr = &w[j * 4 * F_HID];
#pragma unroll
        for (int f = 0; f < F_HID; f++)
            acc[f] += v.x * wr[f] + v.y * wr[F_HID + f] + v.z * wr[2 * F_HID + f] + v.w * wr[3 * F_HID + f];
    }
    float d = dis[node];
    float dsq = d * d;
    float4 lo = make_float4(acc[0], acc[1], acc[2], acc[3]);
    float4 hi = make_float4(acc[4], acc[5], acc[6], acc[7]);
    float4* hp = (float4*)(h1 + (size_t)node * F_HID);
    hp[0] = lo; hp[1] = hi;
    float4* ap = (float4*)(agg1 + (size_t)node * F_HID);
    ap[0] = make_float4(lo.x * dsq, lo.y * dsq, lo.z * dsq, lo.w * dsq);
    ap[1] = make_float4(hi.x * dsq, hi.y * dsq, hi.z * dsq, hi.w * dsq);
}

// ---------------- edge aggregation: agg[dst] += h[src] * dis[src]*dis[dst] ----------------
__global__ __launch_bounds__(256) void edge_agg(const int* __restrict__ ei,
                                                const float* __restrict__ dis,
                                                const float* __restrict__ h,
                                                float* __restrict__ agg, int E) {
    int e = blockIdx.x * blockDim.x + threadIdx.x;
    if (e >= E) return;
    int s = ei[e];
    int d = ei[E + e];
    float nrm = dis[s] * dis[d];
    const float4* hp = (const float4*)(h + (size_t)s * F_HID);
    float4 a = hp[0], b = hp[1];
    float* out = agg + (size_t)d * F_HID;
    atomicAdd(out + 0, a.x * nrm);
    atomicAdd(out + 1, a.y * nrm);
    atomicAdd(out + 2, a.z * nrm);
    atomicAdd(out + 3, a.w * nrm);
    atomicAdd(out + 4, b.x * nrm);
    atomicAdd(out + 5, b.y * nrm);
    atomicAdd(out + 6, b.z * nrm);
    atomicAdd(out + 7, b.w * nrm);
}

// ---------------- relu(agg1 + b1) in-place; agg2 = hr * dis^2 (self-loop init) ----------------
__global__ __launch_bounds__(256) void relu_init(const float* __restrict__ b1,
                                                 const float* __restrict__ dis,
                                                 float* __restrict__ agg1,   // in: agg1, out: hr
                                                 float* __restrict__ agg2, int n) {
    int i = blockIdx.x * blockDim.x + threadIdx.x;
    if (i >= n) return;
    float d = dis[i];
    float dsq = d * d;
    float4* a = (float4*)(agg1 + (size_t)i * F_HID);
    float4 lo = a[0], hi = a[1];
    lo.x = fmaxf(lo.x + b1[0], 0.0f);
    lo.y = fmaxf(lo.y + b1[1], 0.0f);
    lo.z = fmaxf(lo.z + b1[2], 0.0f);
    lo.w = fmaxf(lo.w + b1[3], 0.0f);
    hi.x = fmaxf(hi.x + b1[4], 0.0f);
    hi.y = fmaxf(hi.y + b1[5], 0.0f);
    hi.z = fmaxf(hi.z + b1[6], 0.0f);
    hi.w = fmaxf(hi.w + b1[7], 0.0f);
    a[0] = lo; a[1] = hi;
    float4* o = (float4*)(agg2 + (size_t)i * F_HID);
    o[0] = make_float4(lo.x * dsq, lo.y * dsq, lo.z * dsq, lo.w * dsq);
    o[1] = make_float4(hi.x * dsq, hi.y * dsq, hi.z * dsq, hi.w * dsq);
}

// ---------------- out = agg2 @ W2 + b2 ----------------
__global__ __launch_bounds__(256) void gemm2(const float* __restrict__ agg2,
                                             const float* __restrict__ W2,
                                             const float* __restrict__ b2,
                                             float* __restrict__ out, int n) {
    __shared__ float w[F_HID * F_OUT];  // 128 floats
    __shared__ float bb[F_OUT];
    if (threadIdx.x < F_HID * F_OUT) w[threadIdx.x] = W2[threadIdx.x];
    if (threadIdx.x < F_OUT) bb[threadIdx.x] = b2[threadIdx.x];
    __syncthreads();
    int node = blockIdx.x * blockDim.x + threadIdx.x;
    if (node >= n) return;
    const float4* ap = (const float4*)(agg2 + (size_t)node * F_HID);
    float4 lo = ap[0], hi = ap[1];
    float a[F_HID] = {lo.x, lo.y, lo.z, lo.w, hi.x, hi.y, hi.z, hi.w};
    float o[F_OUT];
#pragma unroll
    for (int f = 0; f < F_OUT; f++) o[f] = bb[f];
#pragma unroll
    for (int k = 0; k < F_HID; k++) {
#pragma unroll
        for (int f = 0; f < F_OUT; f++) o[f] += a[k] * w[k * F_OUT + f];
    }
    float4* op = (float4*)(out + (size_t)node * F_OUT);
    op[0] = make_float4(o[0], o[1], o[2], o[3]);
    op[1] = make_float4(o[4], o[5], o[6], o[7]);
    op[2] = make_float4(o[8], o[9], o[10], o[11]);
    op[3] = make_float4(o[12], o[13], o[14], o[15]);
}

extern "C" void kernel_launch(void* const* d_in, const int* in_sizes, int n_in,
                              void* d_out, int out_size, void* d_ws, size_t ws_size,
                              hipStream_t stream) {
    const float* x  = (const float*)d_in[0];
    const int*   ei = (const int*)d_in[1];   // int64 in reference -> int32 on device
    const float* W1 = (const float*)d_in[2];
    const float* b1 = (const float*)d_in[3];
    const float* W2 = (const float*)d_in[4];
    const float* b2 = (const float*)d_in[5];
    float* out = (float*)d_out;

    const int N = in_sizes[0] / F_IN;
    const int E = in_sizes[1] / 2;

    // workspace layout: dis[N] | h1[N*8] (reused as agg2) | agg1[N*8] (reused as hr)
    float* dis  = (float*)d_ws;
    float* h1   = dis + N;            // later: agg2
    float* agg1 = h1 + (size_t)N * F_HID;

    const int BT = 256;
    dim3 blkN((N + BT - 1) / BT), blkE((E + BT - 1) / BT), thr(BT);

    init_deg<<<blkN, thr, 0, stream>>>(dis, N);
    deg_count<<<blkE, thr, 0, stream>>>(ei, dis, E);
    rsqrt_k<<<blkN, thr, 0, stream>>>(dis, N);
    gemm1<<<blkN, thr, 0, stream>>>(x, W1, dis, h1, agg1, N);
    edge_agg<<<blkE, thr, 0, stream>>>(ei, dis, h1, agg1, E);
    relu_init<<<blkN, thr, 0, stream>>>(b1, dis, agg1, h1 /*agg2*/, N);
    edge_agg<<<blkE, thr, 0, stream>>>(ei, dis, agg1 /*hr*/, h1 /*agg2*/, E);
    gemm2<<<blkN, thr, 0, stream>>>(h1 /*agg2*/, W2, b2, out, N);
}

// Round 3
// 1046.879 us; speedup vs baseline: 5.3912x; 5.3912x over previous
//
#include <hip/hip_runtime.h>

#define F_IN  128
#define F_HID 8
#define F_OUT 16

// edge_index arrives as int32 [2][E] (harness downcasts int64 inputs).

// ---------------- CSR build ----------------
__global__ void init_cnt(int* __restrict__ cnt, int* __restrict__ cursor, int n) {
    int i = blockIdx.x * blockDim.x + threadIdx.x;
    if (i < n) cnt[i] = 0;
    if (i == 0) *cursor = 0;
}

__global__ void count_dst(const int* __restrict__ ei, int* __restrict__ cnt, int E) {
    int e = blockIdx.x * blockDim.x + threadIdx.x;
    if (e < E) atomicAdd(&cnt[ei[E + e]], 1);
}

// deg = cnt + 1 (self-loop); dis = rsqrt(deg); allocate contiguous (unordered) row range
__global__ void calc_offsets(const int* __restrict__ cnt, float* __restrict__ dis,
                             int* __restrict__ row_start, int* __restrict__ row_cur,
                             int* __restrict__ cursor, int n) {
    int i = blockIdx.x * blockDim.x + threadIdx.x;
    if (i >= n) return;
    int c = cnt[i];
    dis[i] = rsqrtf((float)(c + 1));
    int rs = atomicAdd(cursor, c);
    row_start[i] = rs;
    row_cur[i]   = rs;
}

// csr[pos] = {src, norm}; norm = dis[src]*dis[dst] precomputed once, reused by both layers
__global__ __launch_bounds__(256) void fill_csr(const int* __restrict__ ei,
                                                const float* __restrict__ dis,
                                                int* __restrict__ row_cur,
                                                int2* __restrict__ csr, int E) {
    int e = blockIdx.x * blockDim.x + threadIdx.x;
    if (e >= E) return;
    int s = ei[e];
    int d = ei[E + e];
    float nrm = dis[s] * dis[d];
    int pos = atomicAdd(&row_cur[d], 1);
    csr[pos] = make_int2(s, __float_as_int(nrm));
}

// ---------------- layer-1 GEMM: h1 = x @ W1 ; agg1 = h1 * dis^2 (self-loop) ----------------
__global__ __launch_bounds__(256) void gemm1(const float* __restrict__ x,
                                             const float* __restrict__ W1,
                                             const float* __restrict__ dis,
                                             float* __restrict__ h1,
                                             float* __restrict__ agg1, int n) {
    __shared__ float w[F_IN * F_HID];  // 4 KB
    for (int i = threadIdx.x; i < F_IN * F_HID; i += blockDim.x) w[i] = W1[i];
    __syncthreads();
    int node = blockIdx.x * blockDim.x + threadIdx.x;
    if (node >= n) return;
    const float4* xr = (const float4*)(x + (size_t)node * F_IN);
    float acc[F_HID];
#pragma unroll
    for (int f = 0; f < F_HID; f++) acc[f] = 0.0f;
#pragma unroll
    for (int j = 0; j < F_IN / 4; j++) {
        float4 v = xr[j];
        const float* wr = &w[j * 4 * F_HID];
#pragma unroll
        for (int f = 0; f < F_HID; f++)
            acc[f] += v.x * wr[f] + v.y * wr[F_HID + f] + v.z * wr[2 * F_HID + f] + v.w * wr[3 * F_HID + f];
    }
    float d = dis[node];
    float dsq = d * d;
    float4 lo = make_float4(acc[0], acc[1], acc[2], acc[3]);
    float4 hi = make_float4(acc[4], acc[5], acc[6], acc[7]);
    float4* hp = (float4*)(h1 + (size_t)node * F_HID);
    hp[0] = lo; hp[1] = hi;
    float4* ap = (float4*)(agg1 + (size_t)node * F_HID);
    ap[0] = make_float4(lo.x * dsq, lo.y * dsq, lo.z * dsq, lo.w * dsq);
    ap[1] = make_float4(hi.x * dsq, hi.y * dsq, hi.z * dsq, hi.w * dsq);
}

// ---------------- atomic-free aggregation: 8 lanes per node, lane = feature ----------------
__global__ __launch_bounds__(256) void aggregate(const int2* __restrict__ csr,
                                                 const int* __restrict__ row_start,
                                                 const int* __restrict__ cnt,
                                                 const float* __restrict__ h,
                                                 float* __restrict__ agg, int n) {
    int t = blockIdx.x * blockDim.x + threadIdx.x;
    int node = t >> 3;
    int f = t & 7;
    if (node >= n) return;
    int beg = row_start[node];
    int c   = cnt[node];
    float acc = agg[(size_t)node * F_HID + f];  // self-loop contribution already there
    for (int j = 0; j < c; j++) {
        int2 p = csr[beg + j];                  // broadcast within the 8-lane group
        acc += h[(size_t)p.x * F_HID + f] * __int_as_float(p.y);
    }
    agg[(size_t)node * F_HID + f] = acc;
}

// ---------------- relu(agg1 + b1) in-place; agg2 = hr * dis^2 (self-loop init) ----------------
__global__ __launch_bounds__(256) void relu_init(const float* __restrict__ b1,
                                                 const float* __restrict__ dis,
                                                 float* __restrict__ agg1,   // in: agg1, out: hr
                                                 float* __restrict__ agg2, int n) {
    int i = blockIdx.x * blockDim.x + threadIdx.x;
    if (i >= n) return;
    float d = dis[i];
    float dsq = d * d;
    float4* a = (float4*)(agg1 + (size_t)i * F_HID);
    float4 lo = a[0], hi = a[1];
    lo.x = fmaxf(lo.x + b1[0], 0.0f);
    lo.y = fmaxf(lo.y + b1[1], 0.0f);
    lo.z = fmaxf(lo.z + b1[2], 0.0f);
    lo.w = fmaxf(lo.w + b1[3], 0.0f);
    hi.x = fmaxf(hi.x + b1[4], 0.0f);
    hi.y = fmaxf(hi.y + b1[5], 0.0f);
    hi.z = fmaxf(hi.z + b1[6], 0.0f);
    hi.w = fmaxf(hi.w + b1[7], 0.0f);
    a[0] = lo; a[1] = hi;
    float4* o = (float4*)(agg2 + (size_t)i * F_HID);
    o[0] = make_float4(lo.x * dsq, lo.y * dsq, lo.z * dsq, lo.w * dsq);
    o[1] = make_float4(hi.x * dsq, hi.y * dsq, hi.z * dsq, hi.w * dsq);
}

// ---------------- out = agg2 @ W2 + b2 ----------------
__global__ __launch_bounds__(256) void gemm2(const float* __restrict__ agg2,
                                             const float* __restrict__ W2,
                                             const float* __restrict__ b2,
                                             float* __restrict__ out, int n) {
    __shared__ float w[F_HID * F_OUT];
    __shared__ float bb[F_OUT];
    if (threadIdx.x < F_HID * F_OUT) w[threadIdx.x] = W2[threadIdx.x];
    if (threadIdx.x < F_OUT) bb[threadIdx.x] = b2[threadIdx.x];
    __syncthreads();
    int node = blockIdx.x * blockDim.x + threadIdx.x;
    if (node >= n) return;
    const float4* ap = (const float4*)(agg2 + (size_t)node * F_HID);
    float4 lo = ap[0], hi = ap[1];
    float a[F_HID] = {lo.x, lo.y, lo.z, lo.w, hi.x, hi.y, hi.z, hi.w};
    float o[F_OUT];
#pragma unroll
    for (int f = 0; f < F_OUT; f++) o[f] = bb[f];
#pragma unroll
    for (int k = 0; k < F_HID; k++) {
#pragma unroll
        for (int f = 0; f < F_OUT; f++) o[f] += a[k] * w[k * F_OUT + f];
    }
    float4* op = (float4*)(out + (size_t)node * F_OUT);
    op[0] = make_float4(o[0], o[1], o[2], o[3]);
    op[1] = make_float4(o[4], o[5], o[6], o[7]);
    op[2] = make_float4(o[8], o[9], o[10], o[11]);
    op[3] = make_float4(o[12], o[13], o[14], o[15]);
}

extern "C" void kernel_launch(void* const* d_in, const int* in_sizes, int n_in,
                              void* d_out, int out_size, void* d_ws, size_t ws_size,
                              hipStream_t stream) {
    const float* x  = (const float*)d_in[0];
    const int*   ei = (const int*)d_in[1];
    const float* W1 = (const float*)d_in[2];
    const float* b1 = (const float*)d_in[3];
    const float* W2 = (const float*)d_in[4];
    const float* b2 = (const float*)d_in[5];
    float* out = (float*)d_out;

    const int N = in_sizes[0] / F_IN;
    const int E = in_sizes[1] / 2;

    // workspace layout (4B units): csr[2E] (8B-aligned, first) | dis[N] | h1[8N] | agg1[8N]
    //                              | cnt[N] | row_start[N] | row_cur[N] | cursor[1]
    int2*  csr       = (int2*)d_ws;
    float* dis       = (float*)((char*)d_ws + (size_t)E * 8);
    float* h1        = dis + N;                     // later: agg2
    float* agg1      = h1 + (size_t)N * F_HID;      // later: hr
    int*   cnt       = (int*)(agg1 + (size_t)N * F_HID);
    int*   row_start = cnt + N;
    int*   row_cur   = row_start + N;
    int*   cursor    = row_cur + N;

    const int BT = 256;
    dim3 blkN((N + BT - 1) / BT), blkE((E + BT - 1) / BT), thr(BT);
    dim3 blkA(((size_t)N * F_HID + BT - 1) / BT);   // 8 lanes per node

    init_cnt   <<<blkN, thr, 0, stream>>>(cnt, cursor, N);
    count_dst  <<<blkE, thr, 0, stream>>>(ei, cnt, E);
    calc_offsets<<<blkN, thr, 0, stream>>>(cnt, dis, row_start, row_cur, cursor, N);
    fill_csr   <<<blkE, thr, 0, stream>>>(ei, dis, row_cur, csr, E);
    gemm1      <<<blkN, thr, 0, stream>>>(x, W1, dis, h1, agg1, N);
    aggregate  <<<blkA, thr, 0, stream>>>(csr, row_start, cnt, h1, agg1, N);
    relu_init  <<<blkN, thr, 0, stream>>>(b1, dis, agg1, h1 /*agg2*/, N);
    aggregate  <<<blkA, thr, 0, stream>>>(csr, row_start, cnt, agg1 /*hr*/, h1 /*agg2*/, N);
    gemm2      <<<blkN, thr, 0, stream>>>(h1 /*agg2*/, W2, b2, out, N);
}